// Round 11
// baseline (87.887 us; speedup 1.0000x reference)
//
#include <hip/hip_runtime.h>
#include <stdint.h>

typedef float    f32x4  __attribute__((ext_vector_type(4)));
typedef __bf16   bf16x8 __attribute__((ext_vector_type(8)));
typedef uint32_t u32x4  __attribute__((ext_vector_type(4)));
typedef unsigned short u16x4 __attribute__((ext_vector_type(4)));

#define AS1 __attribute__((address_space(1)))
#define AS3 __attribute__((address_space(3)))

__device__ __forceinline__ unsigned short f2bf_bits(float f) {
  uint32_t u = __builtin_bit_cast(uint32_t, f);
  u += 0x7fffu + ((u >> 16) & 1u);      // RNE to bf16
  return (unsigned short)(u >> 16);
}

// ---------------- kernel 0: At[col][k] (bf16) = A[k][col] ----------------
__global__ void k_transpose_cvt(const float* __restrict__ A,
                                unsigned short* __restrict__ At) {
  int n = blockIdx.x * blockDim.x + threadIdx.x;  // 65536 threads
  int o = n << 2;
  int col = o >> 8;
  int k   = o & 255;
  u16x4 v;
#pragma unroll
  for (int j = 0; j < 4; ++j) v[j] = f2bf_bits(A[(size_t)(k + j) * 1024 + col]);
  *reinterpret_cast<u16x4*>(At + o) = v;
}

// ---------------- kernel 1: barrier-free fused GEMM + zero-fill ----------
// 2048 blocks x 64 threads (ONE wave each). Block b: group g=b>>1, half
// h=b&1 -> 32 x-rows (2 MFMA row-groups); fills ROWS h*128..h*128+127 of
// the group slab (contiguous 128KB). Wave-private 2-buffer LDS staging
// (16KB/block -> 8 blocks/CU, 2 waves/SIMD), depth-1 prefetch, counted
// vmcnt, ZERO barriers. Row-sums go to j12 in ws; diag written by k_diag
// (kernel boundary orders it after all fills).
__launch_bounds__(64, 2)
__global__ void k_fused(const float* __restrict__ x,
                        const unsigned short* __restrict__ At,
                        float* __restrict__ out,
                        float* __restrict__ j12) {
  __shared__ alignas(16) char lds[2][8192];

  const int lane = threadIdx.x;          // 0..63
  const int b    = blockIdx.x;
  const int g    = b >> 1;               // group 0..1023
  const int h    = b & 1;                // half (fill rows h*128..)

  const int col = lane & 15;             // A row / B col / C col
  const int hi  = lane >> 4;             // k-subblock select

  uint32_t soff[8];
#pragma unroll
  for (int i = 0; i < 8; ++i) {
    uint32_t p = (uint32_t)(i * 1024 + lane * 16);
    soff[i] = p ^ (((p >> 9) & 7u) << 4);   // involutive XOR swizzle
  }

  // prologue: stage tile 0 into buf 0
#pragma unroll
  for (int i = 0; i < 8; ++i)
    __builtin_amdgcn_global_load_lds((const AS1 uint32_t*)((const char*)At + soff[i]),
                                     (AS3 uint32_t*)(lds[0] + i * 1024), 16, 0, 0);
  __builtin_amdgcn_sched_barrier(0);

  // x fragments: rg r -> x-row g*64 + h*32 + r*16 + col, k = s*32 + hi*8
  bf16x8 xf[2][8];
#pragma unroll
  for (int r = 0; r < 2; ++r) {
    const float* xr = x + (size_t)(g * 64 + h * 32 + r * 16 + col) * 256;
#pragma unroll
    for (int s = 0; s < 8; ++s) {
      f32x4 a = __builtin_nontemporal_load(
          reinterpret_cast<const f32x4*>(xr + s * 32 + hi * 8));
      f32x4 bq = __builtin_nontemporal_load(
          reinterpret_cast<const f32x4*>(xr + s * 32 + hi * 8 + 4));
      bf16x8 f;
      f[0] = (__bf16)a[0];  f[1] = (__bf16)a[1];
      f[2] = (__bf16)a[2];  f[3] = (__bf16)a[3];
      f[4] = (__bf16)bq[0]; f[5] = (__bf16)bq[1];
      f[6] = (__bf16)bq[2]; f[7] = (__bf16)bq[3];
      xf[r][s] = f;
    }
  }
  __builtin_amdgcn_sched_barrier(0);

  float* og = out + (size_t)g * 65536;
  float* fillbase = og + (size_t)h * 32768 + lane * 4;  // rows h*128..
  const f32x4 z4 = {0.f, 0.f, 0.f, 0.f};

  // prologue fills: chunks 60..63 (overlap the x-load latency)
#pragma unroll
  for (int c = 60; c < 64; ++c) {
    float* zp = fillbase + c * 512;
    __builtin_nontemporal_store(z4, reinterpret_cast<f32x4*>(zp));
    __builtin_nontemporal_store(z4, reinterpret_cast<f32x4*>(zp + 256));
  }
  asm volatile("s_waitcnt vmcnt(0)" ::: "memory");   // clean slate for counts

  uint32_t rbase = ((uint32_t)(col * 512 + hi * 16)) ^ ((uint32_t)(col & 7) << 4);
  float sums[2][4] = {{0.f,0.f,0.f,0.f},{0.f,0.f,0.f,0.f}};

  auto do_tile = [&](const char* buf) {
    bf16x8 bfr[8];
#pragma unroll
    for (int s = 0; s < 8; ++s) {
      uint32_t addr = rbase ^ ((uint32_t)s << 6);
      bfr[s] = __builtin_bit_cast(
          bf16x8, *reinterpret_cast<const u32x4*>(buf + addr));
    }
    f32x4 a00 = {0.f,0.f,0.f,0.f}, a01 = {0.f,0.f,0.f,0.f};
    f32x4 a10 = {0.f,0.f,0.f,0.f}, a11 = {0.f,0.f,0.f,0.f};
#pragma unroll
    for (int s = 0; s < 4; ++s) {
      a00 = __builtin_amdgcn_mfma_f32_16x16x32_bf16(xf[0][s],     bfr[s],     a00, 0, 0, 0);
      a01 = __builtin_amdgcn_mfma_f32_16x16x32_bf16(xf[0][s + 4], bfr[s + 4], a01, 0, 0, 0);
      a10 = __builtin_amdgcn_mfma_f32_16x16x32_bf16(xf[1][s],     bfr[s],     a10, 0, 0, 0);
      a11 = __builtin_amdgcn_mfma_f32_16x16x32_bf16(xf[1][s + 4], bfr[s + 4], a11, 0, 0, 0);
    }
#pragma unroll
    for (int j = 0; j < 4; ++j) {
      float z0 = a00[j] + a01[j];
      float z1 = a10[j] + a11[j];
      float s0 = __builtin_amdgcn_rcpf(1.0f + __expf(-z0));
      float s1 = __builtin_amdgcn_rcpf(1.0f + __expf(-z1));
      sums[0][j] += z0 * s0;
      sums[1][j] += z1 * s1;
    }
  };
  auto stage = [&](int t) {
    const char* src = (const char*)At + (size_t)t * 8192;
    char* dst = lds[t & 1];
#pragma unroll
    for (int i = 0; i < 8; ++i)
      __builtin_amdgcn_global_load_lds((const AS1 uint32_t*)(src + soff[i]),
                                       (AS3 uint32_t*)(dst + i * 1024), 16, 0, 0);
  };

  for (int t = 0; t < 60; ++t) {         // uniform [8L, 2S] per iter
    asm volatile("s_waitcnt lgkmcnt(0)" ::: "memory");  // buf[(t+1)&1] reads done
    stage(t + 1);
    __builtin_amdgcn_sched_barrier(0);   // pin [8L] before stores
    {
      float* zp = fillbase + t * 512;    // rows h*128+2t, +1
      __builtin_nontemporal_store(z4, reinterpret_cast<f32x4*>(zp));
      __builtin_nontemporal_store(z4, reinterpret_cast<f32x4*>(zp + 256));
    }
    // younger than tile t's loads: 2S(t-1) + 8L(t+1) + 2S(t) = 12
    asm volatile("s_waitcnt vmcnt(12)" ::: "memory");
    do_tile(lds[t & 1]);
  }
  asm volatile("s_waitcnt lgkmcnt(0)" ::: "memory");
  stage(61);
  asm volatile("s_waitcnt vmcnt(10)" ::: "memory");   // 2S(59)+8L(61)
  do_tile(lds[0]);                                    // t=60
  asm volatile("s_waitcnt lgkmcnt(0)" ::: "memory");
  stage(62);
  asm volatile("s_waitcnt vmcnt(8)" ::: "memory");    // 8L(62)
  do_tile(lds[1]);                                    // t=61
  asm volatile("s_waitcnt lgkmcnt(0)" ::: "memory");
  stage(63);
  asm volatile("s_waitcnt vmcnt(8)" ::: "memory");    // 8L(63)
  do_tile(lds[0]);                                    // t=62
  asm volatile("s_waitcnt vmcnt(0)" ::: "memory");
  do_tile(lds[1]);                                    // t=63

  // reduce over the 16 column-lanes
#pragma unroll
  for (int r = 0; r < 2; ++r)
#pragma unroll
    for (int j = 0; j < 4; ++j) {
      float v = sums[r][j];
      v += __shfl_xor(v, 1, 64);
      v += __shfl_xor(v, 2, 64);
      v += __shfl_xor(v, 4, 64);
      v += __shfl_xor(v, 8, 64);
      sums[r][j] = v;
    }
  if (col == 0) {
#pragma unroll
    for (int r = 0; r < 2; ++r)
#pragma unroll
      for (int j = 0; j < 4; ++j)
        j12[g * 64 + h * 32 + r * 16 + hi * 4 + j] = sums[r][j];
  }
}

// ---------------- kernel 2: diag writes (ordered after k_fused) ----------
__global__ void k_diag(const float* __restrict__ j12,
                       float* __restrict__ out) {
  int t = blockIdx.x * 256 + threadIdx.x;   // 0..65535: (group, x-row)
  int g = t >> 6;
  int c = t & 63;
  float s = j12[t];
  float* og = out + (size_t)g * 65536;
  og[(2 * c) * 256 + 128 + 2 * c]     =  s;
  og[(2 * c + 1) * 256 + 129 + 2 * c] =  s;
  og[(128 + 2 * c) * 256 + 2 * c]     = -s;
  og[(129 + 2 * c) * 256 + 2 * c + 1] = -s;
}

extern "C" void kernel_launch(void* const* d_in, const int* in_sizes, int n_in,
                              void* d_out, int out_size, void* d_ws, size_t ws_size,
                              hipStream_t stream) {
  const float* x = (const float*)d_in[0];   // [65536, 256]
  const float* A = (const float*)d_in[1];   // [256, 1024]
  float* out = (float*)d_out;               // [1024, 256, 256]
  unsigned short* At = (unsigned short*)d_ws;            // 512 KB bf16
  float* j12 = (float*)((char*)d_ws + 512 * 1024);       // 256 KB f32

  k_transpose_cvt<<<256, 256, 0, stream>>>(A, At);
  k_fused<<<2048, 64, 0, stream>>>(x, At, out, j12);
  k_diag<<<256, 256, 0, stream>>>(j12, out);
}